// Round 4
// baseline (192.554 us; speedup 1.0000x reference)
//
#include <hip/hip_runtime.h>
#include <stdint.h>

#define NH   8
#define DIM  512
#define NP   1024
#define MNP  4096
#define BS   4
#define TOPK 32
#define DH   64

typedef unsigned short u16;
typedef __attribute__((ext_vector_type(8))) short bf16x8;
typedef __attribute__((ext_vector_type(4))) float f32x4;

__device__ __forceinline__ u16 f2bf(float f) {
    union { float f; unsigned u; } x; x.f = f;
    unsigned r = x.u + 0x7FFFu + ((x.u >> 16) & 1u);   // RNE
    return (u16)(r >> 16);
}
__device__ __forceinline__ float bf2f(u16 h) {
    union { unsigned u; float f; } x; x.u = ((unsigned)h) << 16;
    return x.f;
}
// HW packed fp32->bf16 RNE: u32 = (bf(b)<<16) | bf(a)   (no builtin on gfx950)
__device__ __forceinline__ unsigned cvt_pk_bf16(float a, float b) {
    unsigned r;
    asm("v_cvt_pk_bf16_f32 %0, %1, %2" : "=v"(r) : "v"(a), "v"(b));
    return r;
}

// ---------------- fused cvt+projection GEMM: reads q/k/v + W1/2/3 fp32
// DIRECTLY (cvt_all kernel eliminated -> saves its ~117 MB HBM round trip and
// one serial dispatch).  128x128x64 tiles, XOR-swizzled LDS granules,
// reg-staged with fp32->bf16 conversion in flight (T14 async-split):
//   LOAD(t+1)->regs  |  MFMA(tile t, buf)      (load latency hides here)
//   cvt+ds_write(t+1 -> buf^1)                 (no reader conflict: other buf)
//   __syncthreads()                            (one barrier per K-step)
__global__ __launch_bounds__(256, 2)
void proj_gemm(const float* __restrict__ qf, const float* __restrict__ kf,
               const float* __restrict__ vf, const float* __restrict__ W1,
               const float* __restrict__ W2, const float* __restrict__ W3,
               const float* __restrict__ b1, const float* __restrict__ b2,
               const float* __restrict__ b3, u16* __restrict__ outall) {
    __shared__ u16 As[2][128 * 64];
    __shared__ u16 Bs[2][128 * 64];

    const int bid = blockIdx.x;        // 0..1151
    const int x = bid / 288;           // n-tile (same-m blocks 288 apart)
    const int t = bid % 288;           // m-tile id across q|k|v
    int z, y;
    if (t < 32)       { z = 0; y = t; }          // q: M=4096  (32 tiles)
    else if (t < 160) { z = 1; y = t - 32; }     // k: M=16384 (128 tiles)
    else              { z = 2; y = t - 160; }    // v: M=16384 (128 tiles)

    const float* Asrc = (z == 0) ? qf : (z == 1) ? kf : vf;
    const float* Wsrc = (z == 0) ? W1 : (z == 1) ? W2 : W3;
    const float* bias = (z == 0) ? b1 : (z == 1) ? b2 : b3;
    const size_t coff = (z == 0) ? 0u : (z == 1) ? 2097152u : 10485760u;
    u16* C = outall + coff;

    const int tid  = threadIdx.x;
    const int bm   = y * 128;
    const int bn   = x * 128;
    const int wave = tid >> 6;
    const int lane = tid & 63;
    const int wm   = (wave & 1) * 64;
    const int wn   = (wave >> 1) * 64;
    const int l16  = lane & 15;
    const int quad = lane >> 4;

    // staging decomposition: thread covers float4 #fi of rows {sr + 16*s}
    const int sr = tid >> 4;           // 0..15 base row
    const int fi = tid & 15;           // float4 index within 64-col window
    const int gq = fi >> 1;            // logical granule (8 bf16)
    const int hf = fi & 1;             // granule half
    // (sr + 16*s) & 7 == sr & 7, so the XOR-swizzled dest offset is s-invariant
    const int ldst = sr * 64 + ((gq ^ (sr & 7)) << 3) + hf * 4;   // u16 elems

    const float* Ab = Asrc + (size_t)(bm + sr) * 512 + fi * 4;
    const float* Wb = Wsrc + (size_t)(bn + sr) * 512 + fi * 4;

    float4 av[8], wv[8];

    // issue 16 global fp32 loads for K-tile at k0 (coalesced 256B/16-lane row)
    #define LOADT(k0)                                                          \
        _Pragma("unroll")                                                      \
        for (int s = 0; s < 8; s++) {                                          \
            av[s] = *(const float4*)(Ab + (size_t)s * 8192 + (k0));            \
            wv[s] = *(const float4*)(Wb + (size_t)s * 8192 + (k0));            \
        }
    // convert + write staged regs into LDS buffer buf (ds_write_b64 each)
    #define WRITET(buf)                                                        \
        _Pragma("unroll")                                                      \
        for (int s = 0; s < 8; s++) {                                          \
            uint2 pa = { cvt_pk_bf16(av[s].x, av[s].y),                        \
                         cvt_pk_bf16(av[s].z, av[s].w) };                      \
            uint2 pw = { cvt_pk_bf16(wv[s].x, wv[s].y),                        \
                         cvt_pk_bf16(wv[s].z, wv[s].w) };                      \
            *(uint2*)&As[buf][ldst + s * 1024] = pa;                           \
            *(uint2*)&Bs[buf][ldst + s * 1024] = pw;                           \
        }

    f32x4 acc[4][4] = {};

    LOADT(0);
    WRITET(0);
    __syncthreads();                   // tile 0 resident

#pragma unroll
    for (int kt = 0; kt < 8; kt++) {
        const int cur = kt & 1;
        if (kt < 7) { LOADT((kt + 1) * 64); }    // regs; latency hides under MFMA
#pragma unroll
        for (int kk = 0; kk < 64; kk += 32) {
            bf16x8 af[4], bfr[4];
            const int g = (kk >> 3) + quad;        // logical granule index
#pragma unroll
            for (int i = 0; i < 4; i++) {
                int ra = wm + i * 16 + l16;
                int rb = wn + i * 16 + l16;
                af[i]  = *(const bf16x8*)(&As[cur][ra * 64 + ((g ^ (ra & 7)) << 3)]);
                bfr[i] = *(const bf16x8*)(&Bs[cur][rb * 64 + ((g ^ (rb & 7)) << 3)]);
            }
#pragma unroll
            for (int i = 0; i < 4; i++)
#pragma unroll
                for (int j = 0; j < 4; j++)
                    acc[i][j] = __builtin_amdgcn_mfma_f32_16x16x32_bf16(
                        af[i], bfr[j], acc[i][j], 0, 0, 0);
        }
        if (kt < 7) {
            WRITET(cur ^ 1);           // other buffer: no conflict with readers
            __syncthreads();           // writes visible; buf cur release for t+2
        }
    }
    #undef LOADT
    #undef WRITET

    // C/D layout: col=lane&15, row=quad*4+reg
#pragma unroll
    for (int i = 0; i < 4; i++) {
        int row = bm + wm + i * 16 + quad * 4;
#pragma unroll
        for (int j = 0; j < 4; j++) {
            int col = bn + wn + j * 16 + l16;
            float bv = bias[col];
#pragma unroll
            for (int r = 0; r < 4; r++)
                C[(size_t)(row + r) * 512 + col] = f2bf(acc[i][j][r] + bv);
        }
    }
}

// ---------------- barrier-free top-k gather attention: one WAVE per (n,b)
__global__ __launch_bounds__(256)
void attn_kernel(const u16* __restrict__ Qh, const u16* __restrict__ Kh,
                 const u16* __restrict__ Vh, const int* __restrict__ rns,
                 float* __restrict__ out) {
    __shared__ float sq[4][512];        // q row fp32, wave-private
    __shared__ float swt[4][32 * 9];    // weights [slot][head], stride-9 pad
    __shared__ int   srw[4][TOPK];      // gathered row offsets

    const int wv   = threadIdx.x >> 6;
    const int lane = threadIdx.x & 63;
    const int pair = blockIdx.x * 4 + wv;   // (n,b) id
    const int n = pair >> 2;
    const int b = pair & 3;
    const int s   = lane >> 1;   // slot
    const int sub = lane & 1;    // dim half

    int myidx = rns[(b * NP + n) * TOPK + s];
    int myrow = (myidx * BS + b) * DIM;
    if (sub == 0) srw[wv][s] = myrow;

    // dedupe: dup iff an earlier slot has the same index (matches ref set-mask)
    bool dup = false;
#pragma unroll
    for (int j = 0; j < TOPK; j++) {
        int other = __shfl(myidx, j * 2, 64);
        dup = dup || ((j < s) && (other == myidx));
    }

    // q row -> LDS fp32 (16B bf16 load per lane)
    {
        const u16* qrow = Qh + (size_t)pair * DIM;
        uint4 qv = *(const uint4*)(qrow + lane * 8);
        float4 f0 = { bf2f((u16)qv.x), bf2f((u16)(qv.x >> 16)),
                      bf2f((u16)qv.y), bf2f((u16)(qv.y >> 16)) };
        float4 f1 = { bf2f((u16)qv.z), bf2f((u16)(qv.z >> 16)),
                      bf2f((u16)qv.w), bf2f((u16)(qv.w >> 16)) };
        *(float4*)(&sq[wv][lane * 8])     = f0;
        *(float4*)(&sq[wv][lane * 8 + 4]) = f1;
    }
    __builtin_amdgcn_wave_barrier();   // wave-private LDS: scheduling pin only

    // scores: each lane computes 8 half-dots (its slot, its 32-dim half)
    const float* qw = sq[wv];
    float sc[NH];
#pragma unroll
    for (int h = 0; h < NH; h++) {
        const u16* kp = Kh + myrow + h * DH + sub * 32;
        const float* qp = qw + h * DH + sub * 32;
        float acc = 0.f;
#pragma unroll
        for (int d = 0; d < 32; d += 8) {
            uint4 kv = *(const uint4*)(kp + d);
            acc += qp[d + 0] * bf2f((u16)kv.x) + qp[d + 1] * bf2f((u16)(kv.x >> 16))
                 + qp[d + 2] * bf2f((u16)kv.y) + qp[d + 3] * bf2f((u16)(kv.y >> 16))
                 + qp[d + 4] * bf2f((u16)kv.z) + qp[d + 5] * bf2f((u16)(kv.z >> 16))
                 + qp[d + 6] * bf2f((u16)kv.w) + qp[d + 7] * bf2f((u16)(kv.w >> 16));
        }
        sc[h] = acc;
    }
#pragma unroll
    for (int h = 0; h < NH; h++) {
        sc[h] += __shfl_xor(sc[h], 1, 64);
        sc[h] = dup ? -1e30f : sc[h] * 0.125f;
    }
    // softmax over 32 slots via stride-{2..32} butterflies
    float w[NH];
#pragma unroll
    for (int h = 0; h < NH; h++) {
        float m = sc[h];
        m = fmaxf(m, __shfl_xor(m, 2, 64));
        m = fmaxf(m, __shfl_xor(m, 4, 64));
        m = fmaxf(m, __shfl_xor(m, 8, 64));
        m = fmaxf(m, __shfl_xor(m, 16, 64));
        m = fmaxf(m, __shfl_xor(m, 32, 64));
        float e = __expf(sc[h] - m);
        float t = e;
        t += __shfl_xor(t, 2, 64);
        t += __shfl_xor(t, 4, 64);
        t += __shfl_xor(t, 8, 64);
        t += __shfl_xor(t, 16, 64);
        t += __shfl_xor(t, 32, 64);
        w[h] = e / t;
    }
    if (sub == 0) {
#pragma unroll
        for (int h = 0; h < NH; h++) swt[wv][s * 9 + h] = w[h];
    }
    __builtin_amdgcn_wave_barrier();

    // V phase: lane covers 8 output elems (16B V load) x 32 slots
    const int h  = lane >> 3;
    const int e8 = lane * 8;
    float a[8] = {0, 0, 0, 0, 0, 0, 0, 0};
#pragma unroll 8
    for (int si = 0; si < TOPK; si++) {
        int   row = srw[wv][si];              // broadcast read
        float wgt = swt[wv][si * 9 + h];      // 8 consecutive addrs: no conflict
        uint4 vv = *(const uint4*)(Vh + row + e8);
        a[0] += wgt * bf2f((u16)vv.x); a[1] += wgt * bf2f((u16)(vv.x >> 16));
        a[2] += wgt * bf2f((u16)vv.y); a[3] += wgt * bf2f((u16)(vv.y >> 16));
        a[4] += wgt * bf2f((u16)vv.z); a[5] += wgt * bf2f((u16)(vv.z >> 16));
        a[6] += wgt * bf2f((u16)vv.w); a[7] += wgt * bf2f((u16)(vv.w >> 16));
    }
    float* op = out + (size_t)pair * DIM + e8;
    float4 o0 = {a[0], a[1], a[2], a[3]};
    float4 o1 = {a[4], a[5], a[6], a[7]};
    *(float4*)op       = o0;
    *((float4*)op + 1) = o1;
}

extern "C" void kernel_launch(void* const* d_in, const int* in_sizes, int n_in,
                              void* d_out, int out_size, void* d_ws, size_t ws_size,
                              hipStream_t stream) {
    const float* q  = (const float*)d_in[0];
    const float* k  = (const float*)d_in[1];
    const float* v  = (const float*)d_in[2];
    const int* rns  = (const int*)d_in[3];
    const float* W1 = (const float*)d_in[4];
    const float* b1 = (const float*)d_in[5];
    const float* W2 = (const float*)d_in[6];
    const float* b2 = (const float*)d_in[7];
    const float* W3 = (const float*)d_in[8];
    const float* b3 = (const float*)d_in[9];
    float* out = (float*)d_out;

    // workspace: only the projected Qh|Kh|Vh bf16 (cvt_all + act/wall removed)
    u16* proj = (u16*)d_ws;
    u16* Qh = proj;
    u16* Kh = proj + 2097152;
    u16* Vh = proj + 10485760;

    proj_gemm<<<1152, 256, 0, stream>>>(q, k, v, W1, W2, W3, b1, b2, b3, proj);
    attn_kernel<<<NP * BS / 4, 256, 0, stream>>>(Qh, Kh, Vh, rns, out);
}